// Round 1
// 135.952 us; speedup vs baseline: 1.0003x; 1.0003x over previous
//
#include <hip/hip_runtime.h>
#include <hip/hip_bf16.h>

typedef __attribute__((ext_vector_type(8))) short bf16x8;
typedef __attribute__((ext_vector_type(4))) float f32x4;

__device__ __forceinline__ float sigmoidf_(float v) {
    return 1.0f / (1.0f + __expf(-v));
}
__device__ __forceinline__ short f2bf(float f) {
    union { __hip_bfloat16 h; short s; } cv;
    cv.h = __float2bfloat16(f);
    return cv.s;
}
__device__ __forceinline__ float bf2f(short s) {
    union { float f; unsigned u; } cv;
    cv.u = ((unsigned)(unsigned short)s) << 16;
    return cv.f;
}

// ---------------------------------------------------------------------------
// Kernel 0: conversions, all coalesced.
//  b in [0,256)  : xb[1024][512] = bf16(x), 8 elems/thread
//  b in [256,320): transpose pp_w1 [512k][512n] -> Wt rows 0..511
//  b in [320,384): transpose cd_w1 [1024k][256n] -> Wt rows 512..1023 (U|V)
//  b in [384,392): transpose cd_w2 [256k][128n] -> w2t [128][256]
//  b == 392      : pack hw[10][512]: pp_w2 cols 0-3, vel_w cols, frc_w cols
// ---------------------------------------------------------------------------
__global__ __launch_bounds__(256) void convert_kernel(
    const float* __restrict__ x, const float* __restrict__ pp_w1,
    const float* __restrict__ cd_w1, const float* __restrict__ cd_w2,
    const float* __restrict__ pp_w2, const float* __restrict__ vel_w,
    const float* __restrict__ frc_w,
    __hip_bfloat16* __restrict__ xb, __hip_bfloat16* __restrict__ Wt,
    __hip_bfloat16* __restrict__ w2t, float* __restrict__ hw)
{
    __shared__ float ts[64][65];
    const int b = blockIdx.x, t = threadIdx.x;

    if (b < 256) {  // xb cast
        int base = b * 2048 + t * 8;
        float4 a = *(const float4*)(x + base);
        float4 c = *(const float4*)(x + base + 4);
        bf16x8 o;
        o[0] = f2bf(a.x); o[1] = f2bf(a.y); o[2] = f2bf(a.z); o[3] = f2bf(a.w);
        o[4] = f2bf(c.x); o[5] = f2bf(c.y); o[6] = f2bf(c.z); o[7] = f2bf(c.w);
        *(bf16x8*)(xb + base) = o;
        return;
    }
    if (b == 392) {  // hw pack (tiny, strided reads but only 5120 elems)
        for (int e = t; e < 5120; e += 256) {
            int h = e >> 9, k = e & 511;
            float v = (h < 4) ? pp_w2[k * 128 + h]
                    : (h < 7) ? vel_w[k * 3 + (h - 4)]
                              : frc_w[k * 3 + (h - 7)];
            hw[e] = v;
        }
        return;
    }

    // --- 64x64 tile transpose regions ---
    const float* src; int ss, k0, n0, region;
    if (b < 320)      { int i = b - 256; src = pp_w1; ss = 512; k0 = (i >> 3) * 64; n0 = (i & 7) * 64; region = 0; }
    else if (b < 384) { int i = b - 320; src = cd_w1; ss = 256; k0 = (i >> 2) * 64; n0 = (i & 3) * 64; region = 1; }
    else              { int i = b - 384; src = cd_w2; ss = 128; k0 = (i >> 1) * 64; n0 = (i & 1) * 64; region = 2; }

    #pragma unroll
    for (int i = 0; i < 4; ++i) {   // read coalesced
        int r = (t >> 4) + i * 16, c4 = (t & 15) * 4;
        *(float4*)&ts[r][c4] = *(const float4*)(src + (k0 + r) * ss + n0 + c4);
    }
    __syncthreads();
    #pragma unroll
    for (int i = 0; i < 4; ++i) {   // write transposed, coalesced in k
        int nOut = (t >> 4) + i * 16, kc = (t & 15) * 4;
        ushort4 o;
        o.x = (unsigned short)f2bf(ts[kc + 0][nOut]);
        o.y = (unsigned short)f2bf(ts[kc + 1][nOut]);
        o.z = (unsigned short)f2bf(ts[kc + 2][nOut]);
        o.w = (unsigned short)f2bf(ts[kc + 3][nOut]);
        int gn = n0 + nOut, gk = k0 + kc;
        if (region == 0)      *(ushort4*)(Wt + gn * 512 + gk) = o;
        else if (region == 1) {
            int row = (gk < 512) ? (512 + gn) : (768 + gn);
            *(ushort4*)(Wt + row * 512 + (gk & 511)) = o;
        } else                *(ushort4*)(w2t + gn * 256 + gk) = o;
    }
}

// ---------------------------------------------------------------------------
// Kernel 1: fused MFMA GEMM C[1024][1024] = xb @ Wt^T. 2x2 tile per wave
// (32 rows x 32 cols), fragments straight from L2. grid (8 n-blocks, 32 m).
// ---------------------------------------------------------------------------
__global__ __launch_bounds__(256) void gemm_kernel(
    const __hip_bfloat16* __restrict__ xb, const __hip_bfloat16* __restrict__ Wt,
    const float* __restrict__ pp_b1, const float* __restrict__ cd_b1,
    __hip_bfloat16* __restrict__ hidg, float* __restrict__ Ug,
    float* __restrict__ Vg)
{
    const int t = threadIdx.x;
    const int wave = t >> 6, lane = t & 63;
    const int l = lane & 15, q = lane >> 4;
    const int m0 = blockIdx.y * 32;
    const int n0 = blockIdx.x * 128 + wave * 32;

    const __hip_bfloat16* a0p = xb + (m0 + l) * 512 + q * 8;
    const __hip_bfloat16* a1p = a0p + 16 * 512;
    const __hip_bfloat16* b0p = Wt + (n0 + l) * 512 + q * 8;
    const __hip_bfloat16* b1p = b0p + 16 * 512;

    f32x4 acc00 = {}, acc01 = {}, acc10 = {}, acc11 = {};
    #pragma unroll
    for (int ks = 0; ks < 16; ++ks) {
        bf16x8 a0 = *(const bf16x8*)(a0p + ks * 32);
        bf16x8 a1 = *(const bf16x8*)(a1p + ks * 32);
        bf16x8 b0 = *(const bf16x8*)(b0p + ks * 32);
        bf16x8 b1 = *(const bf16x8*)(b1p + ks * 32);
        acc00 = __builtin_amdgcn_mfma_f32_16x16x32_bf16(a0, b0, acc00, 0, 0, 0);
        acc01 = __builtin_amdgcn_mfma_f32_16x16x32_bf16(a0, b1, acc01, 0, 0, 0);
        acc10 = __builtin_amdgcn_mfma_f32_16x16x32_bf16(a1, b0, acc10, 0, 0, 0);
        acc11 = __builtin_amdgcn_mfma_f32_16x16x32_bf16(a1, b1, acc11, 0, 0, 0);
    }

    // C/D layout: col = l, row = q*4 + r
    const int c0 = n0 + l, c1 = n0 + 16 + l;
    #pragma unroll
    for (int mt = 0; mt < 2; ++mt) {
        const f32x4& A0 = mt ? acc10 : acc00;
        const f32x4& A1 = mt ? acc11 : acc01;
        if (n0 < 512) {
            float b0v = pp_b1[c0], b1v = pp_b1[c1];
            #pragma unroll
            for (int r = 0; r < 4; ++r) {
                int rg = m0 + mt * 16 + q * 4 + r;
                hidg[rg * 512 + c0] = __float2bfloat16(fmaxf(A0[r] + b0v, 0.f));
                hidg[rg * 512 + c1] = __float2bfloat16(fmaxf(A1[r] + b1v, 0.f));
            }
        } else if (n0 < 768) {
            float b0v = cd_b1[c0 - 512], b1v = cd_b1[c1 - 512];
            #pragma unroll
            for (int r = 0; r < 4; ++r) {
                int rg = m0 + mt * 16 + q * 4 + r;
                Ug[rg * 256 + (c0 - 512)] = A0[r] + b0v;
                Ug[rg * 256 + (c1 - 512)] = A1[r] + b1v;
            }
        } else {
            #pragma unroll
            for (int r = 0; r < 4; ++r) {
                int rg = m0 + mt * 16 + q * 4 + r;
                Vg[rg * 256 + (c0 - 768)] = A0[r] + 0.f;
                Vg[rg * 256 + (c1 - 768)] = A1[r] + 0.f;
            }
        }
    }
}

// ---------------------------------------------------------------------------
// Kernel 2: pair MLP + heads (merged; heads are blockIdx.x >= 528).
// Pair part: hs = bf16(relu(U_i+V_j)) staged ONCE per block into XOR-swizzled
// LDS (removes the 4x per-wave A-fragment VALU redundancy); each wave then
// ds_read_b128's its MFMA A-fragments directly. B-fragments straight from L2.
// ---------------------------------------------------------------------------
__global__ __launch_bounds__(256) void pair_kernel(
    const float* __restrict__ Ug, const float* __restrict__ Vg,
    const __hip_bfloat16* __restrict__ w2t,  // [128][256] bf16
    const float* __restrict__ cd_b2, const float* __restrict__ cd_w3,
    const float* __restrict__ cd_b3, float* __restrict__ cm,
    const float* __restrict__ x, const __hip_bfloat16* __restrict__ hidg,
    const float* __restrict__ hw, const float* __restrict__ pp_b2,
    const float* __restrict__ vel_b, const float* __restrict__ frc_b,
    float* __restrict__ out)
{
    __shared__ __align__(16) __hip_bfloat16 hs[16384];  // [64 pairs][256 k], swizzled
    __shared__ float ps[64][4];

    const int t = threadIdx.x;
    const int wave = t >> 6, lane = t & 63;

    if (blockIdx.x >= 528) {
        // ---- heads: one wave per row; 10 coalesced shuffle-reduce dots ----
        const int row = blockIdx.y * 256 + (blockIdx.x - 528) * 4 + wave;
        const float4* xr = (const float4*)(x + row * 512);
        float4 xa = xr[lane * 2], xc = xr[lane * 2 + 1];
        bf16x8 hb = *(const bf16x8*)(hidg + row * 512 + lane * 8);
        float hf[8];
        #pragma unroll
        for (int j = 0; j < 8; ++j) hf[j] = bf2f(hb[j]);

        #pragma unroll
        for (int h = 0; h < 10; ++h) {
            const float4* wr = (const float4*)(hw + h * 512);
            float4 wa = wr[lane * 2], wc = wr[lane * 2 + 1];
            float s;
            if (h < 4) {
                s = hf[0]*wa.x + hf[1]*wa.y + hf[2]*wa.z + hf[3]*wa.w
                  + hf[4]*wc.x + hf[5]*wc.y + hf[6]*wc.z + hf[7]*wc.w;
            } else {
                s = xa.x*wa.x + xa.y*wa.y + xa.z*wa.z + xa.w*wa.w
                  + xc.x*wc.x + xc.y*wc.y + xc.z*wc.z + xc.w*wc.w;
            }
            s += __shfl_xor(s, 1);  s += __shfl_xor(s, 2);
            s += __shfl_xor(s, 4);  s += __shfl_xor(s, 8);
            s += __shfl_xor(s, 16); s += __shfl_xor(s, 32);
            if (lane == 0) {
                if (h < 4) {
                    float sg = sigmoidf_(s + pp_b2[h]);
                    out[h * 1024 + row] = (h == 0) ? sg * 100.f : (h == 3) ? sg * 10.f : sg;
                } else if (h < 7) {
                    out[4096 + row * 3 + (h - 4)] = s + vel_b[h - 4];
                } else {
                    out[7168 + row * 3 + (h - 7)] = s + frc_b[h - 7];
                }
            }
        }
        return;
    }

    // ---- pair part ----
    const int b = blockIdx.y;
    const int tp = blockIdx.x;  // 0..527, (ti<=tj) of 32x32 tiles
    // decode triangular: S(t) = t*(65-t)/2
    int ti = (int)((65.0f - sqrtf(4225.0f - 8.0f * (float)tp)) * 0.5f);
    while ((ti + 1) * (65 - (ti + 1)) / 2 <= tp) ++ti;
    while (ti * (65 - ti) / 2 > tp) --ti;
    const int tj = ti + (tp - ti * (65 - ti) / 2);

    const int i0 = ti * 8, j0 = tj * 8;

    // Stage hs[p][k] = bf16(relu(U[i0+p>>3][k] + V[j0+p&7][k])), p in [0,64).
    // Byte layout: p*512 + k*2, XOR bits 4-6 with (p&7) to kill the
    // 512B-row-stride same-bank pattern on the ds_read_b128 side.
    {
        const float* Ub = Ug + (b * 256 + i0) * 256;
        const float* Vb = Vg + (b * 256 + j0) * 256;
        #pragma unroll
        for (int w = 0; w < 8; ++w) {
            int idx = (w << 8) + t;          // [64 pairs][32 chunks of 8]
            int p = idx >> 5, c = idx & 31;
            const float* up = Ub + (p >> 3) * 256 + c * 8;
            const float* vp = Vb + (p & 7) * 256 + c * 8;
            float4 u0 = *(const float4*)up, u1 = *(const float4*)(up + 4);
            float4 v0 = *(const float4*)vp, v1 = *(const float4*)(vp + 4);
            bf16x8 o;
            o[0] = f2bf(fmaxf(u0.x + v0.x, 0.f));
            o[1] = f2bf(fmaxf(u0.y + v0.y, 0.f));
            o[2] = f2bf(fmaxf(u0.z + v0.z, 0.f));
            o[3] = f2bf(fmaxf(u0.w + v0.w, 0.f));
            o[4] = f2bf(fmaxf(u1.x + v1.x, 0.f));
            o[5] = f2bf(fmaxf(u1.y + v1.y, 0.f));
            o[6] = f2bf(fmaxf(u1.z + v1.z, 0.f));
            o[7] = f2bf(fmaxf(u1.w + v1.w, 0.f));
            int byte = (p << 9) + (c << 4);
            byte ^= (p & 7) << 4;
            *(bf16x8*)((char*)hs + byte) = o;
        }
    }
    __syncthreads();

    const int l = lane & 15, q = lane >> 4;
    const __hip_bfloat16* wb0 = w2t + ((wave * 2 + 0) * 16 + l) * 256 + q * 8;
    const __hip_bfloat16* wb1 = wb0 + 16 * 256;
    const char* hsb = (const char*)hs;
    const int xorv = (l & 7) << 4;           // row&7 == l&7 (rows step by 16)
    const int rbase = (l << 9) + (q << 4);   // row=l, k=q*8 within 32-k step

    f32x4 acc[4][2] = {};
    #pragma unroll
    for (int ks = 0; ks < 8; ++ks) {
        bf16x8 bfr0 = *(const bf16x8*)(wb0 + ks * 32);
        bf16x8 bfr1 = *(const bf16x8*)(wb1 + ks * 32);
        #pragma unroll
        for (int mt = 0; mt < 4; ++mt) {
            int byte = (mt << 13) + rbase + (ks << 6);  // (mt*16+l)*512 + ks*64 + q*16
            bf16x8 afr = *(const bf16x8*)(hsb + (byte ^ xorv));
            acc[mt][0] = __builtin_amdgcn_mfma_f32_16x16x32_bf16(afr, bfr0, acc[mt][0], 0, 0, 0);
            acc[mt][1] = __builtin_amdgcn_mfma_f32_16x16x32_bf16(afr, bfr1, acc[mt][1], 0, 0, 0);
        }
    }

    // epilogue: +b2, relu, dot w3 over wave's 32 cols, 16-lane shuffle reduce
    float b2v0 = cd_b2[(wave * 2 + 0) * 16 + l], b2v1 = cd_b2[(wave * 2 + 1) * 16 + l];
    float w3v0 = cd_w3[(wave * 2 + 0) * 16 + l], w3v1 = cd_w3[(wave * 2 + 1) * 16 + l];
    #pragma unroll
    for (int mt = 0; mt < 4; ++mt) {
        #pragma unroll
        for (int r = 0; r < 4; ++r) {
            // D layout: pair = mt*16 + q*4 + r, col = nt*16 + l
            float g0 = fmaxf(acc[mt][0][r] + b2v0, 0.f);
            float g1 = fmaxf(acc[mt][1][r] + b2v1, 0.f);
            float s = g0 * w3v0 + g1 * w3v1;
            s += __shfl_xor(s, 1);
            s += __shfl_xor(s, 2);
            s += __shfl_xor(s, 4);
            s += __shfl_xor(s, 8);
            if (l == 0) ps[mt * 16 + q * 4 + r][wave] = s;
        }
    }
    __syncthreads();

    if (t < 64) {
        int p = t;
        float v = ps[p][0] + ps[p][1] + ps[p][2] + ps[p][3] + cd_b3[0];
        float prob = 1.0f / (1.0f + __expf(-v));
        int i = i0 + (p >> 3), j = j0 + (p & 7);
        float* base = cm + b * 65536;
        if (i < j) {
            base[i * 256 + j] = prob;
            base[j * 256 + i] = prob;
        } else if (i == j) {
            base[i * 256 + i] = 0.0f;
        }
    }
}

// ---------------------------------------------------------------------------
extern "C" void kernel_launch(void* const* d_in, const int* in_sizes, int n_in,
                              void* d_out, int out_size, void* d_ws, size_t ws_size,
                              hipStream_t stream) {
    const float* x     = (const float*)d_in[0];
    const float* pp_w1 = (const float*)d_in[1];
    const float* pp_b1 = (const float*)d_in[2];
    const float* pp_w2 = (const float*)d_in[3];
    const float* pp_b2 = (const float*)d_in[4];
    const float* cd_w1 = (const float*)d_in[5];
    const float* cd_b1 = (const float*)d_in[6];
    const float* cd_w2 = (const float*)d_in[7];
    const float* cd_b2 = (const float*)d_in[8];
    const float* cd_w3 = (const float*)d_in[9];
    const float* cd_b3 = (const float*)d_in[10];
    const float* vel_w = (const float*)d_in[11];
    const float* vel_b = (const float*)d_in[12];
    const float* frc_w = (const float*)d_in[13];
    const float* frc_b = (const float*)d_in[14];

    float* out = (float*)d_out;
    // ws: Ug 1MB | Vg 1MB | xb 1MB | Wt 1MB | hidg 1MB | w2t 64KB | hw 20KB
    float* Ug = (float*)d_ws;
    float* Vg = Ug + 262144;
    __hip_bfloat16* xb   = (__hip_bfloat16*)(Vg + 262144);
    __hip_bfloat16* Wt   = xb + 524288;
    __hip_bfloat16* hidg = Wt + 524288;
    __hip_bfloat16* w2t  = hidg + 524288;
    float* hw = (float*)(w2t + 32768);

    convert_kernel<<<dim3(393), dim3(256), 0, stream>>>(
        x, pp_w1, cd_w1, cd_w2, pp_w2, vel_w, frc_w, xb, Wt, w2t, hw);
    gemm_kernel<<<dim3(8, 32), dim3(256), 0, stream>>>(
        xb, Wt, pp_b1, cd_b1, hidg, Ug, Vg);
    pair_kernel<<<dim3(592, 4), dim3(256), 0, stream>>>(
        Ug, Vg, w2t, cd_b2, cd_w3, cd_b3, out + 10240,
        x, hidg, hw, pp_b2, vel_b, frc_b, out);
}

// Round 2
// 134.814 us; speedup vs baseline: 1.0088x; 1.0084x over previous
//
#include <hip/hip_runtime.h>
#include <hip/hip_bf16.h>

typedef __attribute__((ext_vector_type(8))) short bf16x8;
typedef __attribute__((ext_vector_type(4))) float f32x4;

__device__ __forceinline__ float sigmoidf_(float v) {
    return 1.0f / (1.0f + __expf(-v));
}
__device__ __forceinline__ short f2bf(float f) {
    union { __hip_bfloat16 h; short s; } cv;
    cv.h = __float2bfloat16(f);
    return cv.s;
}
__device__ __forceinline__ float bf2f(short s) {
    union { float f; unsigned u; } cv;
    cv.u = ((unsigned)(unsigned short)s) << 16;
    return cv.f;
}

// ---------------------------------------------------------------------------
// Kernel 0: conversions, all coalesced.
//  b in [0,256)  : xb[1024][512] = bf16(x), 8 elems/thread
//  b in [256,320): transpose pp_w1 [512k][512n] -> Wt rows 0..511
//  b in [320,384): transpose cd_w1 [1024k][256n] -> Wt rows 512..1023 (U|V)
//  b in [384,392): transpose cd_w2 [256k][128n] -> w2t [128][256]
//  b == 392      : pack hw[10][512]: pp_w2 cols 0-3, vel_w cols, frc_w cols
// ---------------------------------------------------------------------------
__global__ __launch_bounds__(256) void convert_kernel(
    const float* __restrict__ x, const float* __restrict__ pp_w1,
    const float* __restrict__ cd_w1, const float* __restrict__ cd_w2,
    const float* __restrict__ pp_w2, const float* __restrict__ vel_w,
    const float* __restrict__ frc_w,
    __hip_bfloat16* __restrict__ xb, __hip_bfloat16* __restrict__ Wt,
    __hip_bfloat16* __restrict__ w2t, float* __restrict__ hw)
{
    __shared__ float ts[64][65];
    const int b = blockIdx.x, t = threadIdx.x;

    if (b < 256) {  // xb cast
        int base = b * 2048 + t * 8;
        float4 a = *(const float4*)(x + base);
        float4 c = *(const float4*)(x + base + 4);
        bf16x8 o;
        o[0] = f2bf(a.x); o[1] = f2bf(a.y); o[2] = f2bf(a.z); o[3] = f2bf(a.w);
        o[4] = f2bf(c.x); o[5] = f2bf(c.y); o[6] = f2bf(c.z); o[7] = f2bf(c.w);
        *(bf16x8*)(xb + base) = o;
        return;
    }
    if (b == 392) {  // hw pack (tiny, strided reads but only 5120 elems)
        for (int e = t; e < 5120; e += 256) {
            int h = e >> 9, k = e & 511;
            float v = (h < 4) ? pp_w2[k * 128 + h]
                    : (h < 7) ? vel_w[k * 3 + (h - 4)]
                              : frc_w[k * 3 + (h - 7)];
            hw[e] = v;
        }
        return;
    }

    // --- 64x64 tile transpose regions ---
    const float* src; int ss, k0, n0, region;
    if (b < 320)      { int i = b - 256; src = pp_w1; ss = 512; k0 = (i >> 3) * 64; n0 = (i & 7) * 64; region = 0; }
    else if (b < 384) { int i = b - 320; src = cd_w1; ss = 256; k0 = (i >> 2) * 64; n0 = (i & 3) * 64; region = 1; }
    else              { int i = b - 384; src = cd_w2; ss = 128; k0 = (i >> 1) * 64; n0 = (i & 1) * 64; region = 2; }

    #pragma unroll
    for (int i = 0; i < 4; ++i) {   // read coalesced
        int r = (t >> 4) + i * 16, c4 = (t & 15) * 4;
        *(float4*)&ts[r][c4] = *(const float4*)(src + (k0 + r) * ss + n0 + c4);
    }
    __syncthreads();
    #pragma unroll
    for (int i = 0; i < 4; ++i) {   // write transposed, coalesced in k
        int nOut = (t >> 4) + i * 16, kc = (t & 15) * 4;
        ushort4 o;
        o.x = (unsigned short)f2bf(ts[kc + 0][nOut]);
        o.y = (unsigned short)f2bf(ts[kc + 1][nOut]);
        o.z = (unsigned short)f2bf(ts[kc + 2][nOut]);
        o.w = (unsigned short)f2bf(ts[kc + 3][nOut]);
        int gn = n0 + nOut, gk = k0 + kc;
        if (region == 0)      *(ushort4*)(Wt + gn * 512 + gk) = o;
        else if (region == 1) {
            int row = (gk < 512) ? (512 + gn) : (768 + gn);
            *(ushort4*)(Wt + row * 512 + (gk & 511)) = o;
        } else                *(ushort4*)(w2t + gn * 256 + gk) = o;
    }
}

// ---------------------------------------------------------------------------
// Kernel 1: fused MFMA GEMM C[1024][1024] = xb @ Wt^T. 2x2 tile per wave
// (32 rows x 32 cols), fragments straight from L2. grid (8 n-blocks, 32 m).
// ---------------------------------------------------------------------------
__global__ __launch_bounds__(256) void gemm_kernel(
    const __hip_bfloat16* __restrict__ xb, const __hip_bfloat16* __restrict__ Wt,
    const float* __restrict__ pp_b1, const float* __restrict__ cd_b1,
    __hip_bfloat16* __restrict__ hidg, float* __restrict__ Ug,
    float* __restrict__ Vg)
{
    const int t = threadIdx.x;
    const int wave = t >> 6, lane = t & 63;
    const int l = lane & 15, q = lane >> 4;
    const int m0 = blockIdx.y * 32;
    const int n0 = blockIdx.x * 128 + wave * 32;

    const __hip_bfloat16* a0p = xb + (m0 + l) * 512 + q * 8;
    const __hip_bfloat16* a1p = a0p + 16 * 512;
    const __hip_bfloat16* b0p = Wt + (n0 + l) * 512 + q * 8;
    const __hip_bfloat16* b1p = b0p + 16 * 512;

    f32x4 acc00 = {}, acc01 = {}, acc10 = {}, acc11 = {};
    #pragma unroll
    for (int ks = 0; ks < 16; ++ks) {
        bf16x8 a0 = *(const bf16x8*)(a0p + ks * 32);
        bf16x8 a1 = *(const bf16x8*)(a1p + ks * 32);
        bf16x8 b0 = *(const bf16x8*)(b0p + ks * 32);
        bf16x8 b1 = *(const bf16x8*)(b1p + ks * 32);
        acc00 = __builtin_amdgcn_mfma_f32_16x16x32_bf16(a0, b0, acc00, 0, 0, 0);
        acc01 = __builtin_amdgcn_mfma_f32_16x16x32_bf16(a0, b1, acc01, 0, 0, 0);
        acc10 = __builtin_amdgcn_mfma_f32_16x16x32_bf16(a1, b0, acc10, 0, 0, 0);
        acc11 = __builtin_amdgcn_mfma_f32_16x16x32_bf16(a1, b1, acc11, 0, 0, 0);
    }

    // C/D layout: col = l, row = q*4 + r
    const int c0 = n0 + l, c1 = n0 + 16 + l;
    #pragma unroll
    for (int mt = 0; mt < 2; ++mt) {
        const f32x4& A0 = mt ? acc10 : acc00;
        const f32x4& A1 = mt ? acc11 : acc01;
        if (n0 < 512) {
            float b0v = pp_b1[c0], b1v = pp_b1[c1];
            #pragma unroll
            for (int r = 0; r < 4; ++r) {
                int rg = m0 + mt * 16 + q * 4 + r;
                hidg[rg * 512 + c0] = __float2bfloat16(fmaxf(A0[r] + b0v, 0.f));
                hidg[rg * 512 + c1] = __float2bfloat16(fmaxf(A1[r] + b1v, 0.f));
            }
        } else if (n0 < 768) {
            float b0v = cd_b1[c0 - 512], b1v = cd_b1[c1 - 512];
            #pragma unroll
            for (int r = 0; r < 4; ++r) {
                int rg = m0 + mt * 16 + q * 4 + r;
                Ug[rg * 256 + (c0 - 512)] = A0[r] + b0v;
                Ug[rg * 256 + (c1 - 512)] = A1[r] + b1v;
            }
        } else {
            #pragma unroll
            for (int r = 0; r < 4; ++r) {
                int rg = m0 + mt * 16 + q * 4 + r;
                Vg[rg * 256 + (c0 - 768)] = A0[r];
                Vg[rg * 256 + (c1 - 768)] = A1[r];
            }
        }
    }
}

// ---------------------------------------------------------------------------
// Kernel 2: pair MLP + heads, software-pipelined.
// Pair blocks (bx<528): one block owns one 8x8 pair-tile for ALL 4 batches.
// Each batch is split into two K=128 halves -> 8 pipeline steps. Per step:
//   ISSUE loads(next half)->regs | MFMA(prev half from LDS dbuf) |
//   epilogue/final (1-2 steps back) | convert+ds_write(next half) | barrier.
// LDS: 2 x 16KB half-buffers (XOR-swizzled) + 2KB ps. Heads: bx in [528,656).
// ---------------------------------------------------------------------------
__global__ __launch_bounds__(256) void pair_kernel(
    const float* __restrict__ Ug, const float* __restrict__ Vg,
    const __hip_bfloat16* __restrict__ w2t,  // [128][256] bf16
    const float* __restrict__ cd_b2, const float* __restrict__ cd_w3,
    const float* __restrict__ cd_b3, float* __restrict__ cm,
    const float* __restrict__ x, const __hip_bfloat16* __restrict__ hidg,
    const float* __restrict__ hw, const float* __restrict__ pp_b2,
    const float* __restrict__ vel_b, const float* __restrict__ frc_b,
    float* __restrict__ out)
{
    __shared__ __align__(16) __hip_bfloat16 hsH[2][8192];  // 2 x [64 pairs][128 k]
    __shared__ float ps[2][64][4];

    const int t = threadIdx.x;
    const int wave = t >> 6, lane = t & 63;
    const int bx = blockIdx.x;

    if (bx >= 528) {
        // ---- heads: 128 blocks, wave handles 2 rows; 10 shuffle-reduce dots ----
        #pragma unroll
        for (int rr = 0; rr < 2; ++rr) {
            const int row = (bx - 528) * 8 + wave * 2 + rr;
            const float4* xr = (const float4*)(x + row * 512);
            float4 xa = xr[lane * 2], xc = xr[lane * 2 + 1];
            bf16x8 hb = *(const bf16x8*)(hidg + row * 512 + lane * 8);
            float hf[8];
            #pragma unroll
            for (int j = 0; j < 8; ++j) hf[j] = bf2f(hb[j]);

            #pragma unroll
            for (int h = 0; h < 10; ++h) {
                const float4* wr = (const float4*)(hw + h * 512);
                float4 wa = wr[lane * 2], wc = wr[lane * 2 + 1];
                float s;
                if (h < 4) {
                    s = hf[0]*wa.x + hf[1]*wa.y + hf[2]*wa.z + hf[3]*wa.w
                      + hf[4]*wc.x + hf[5]*wc.y + hf[6]*wc.z + hf[7]*wc.w;
                } else {
                    s = xa.x*wa.x + xa.y*wa.y + xa.z*wa.z + xa.w*wa.w
                      + xc.x*wc.x + xc.y*wc.y + xc.z*wc.z + xc.w*wc.w;
                }
                s += __shfl_xor(s, 1);  s += __shfl_xor(s, 2);
                s += __shfl_xor(s, 4);  s += __shfl_xor(s, 8);
                s += __shfl_xor(s, 16); s += __shfl_xor(s, 32);
                if (lane == 0) {
                    if (h < 4) {
                        float sg = sigmoidf_(s + pp_b2[h]);
                        out[h * 1024 + row] = (h == 0) ? sg * 100.f : (h == 3) ? sg * 10.f : sg;
                    } else if (h < 7) {
                        out[4096 + row * 3 + (h - 4)] = s + vel_b[h - 4];
                    } else {
                        out[7168 + row * 3 + (h - 7)] = s + frc_b[h - 7];
                    }
                }
            }
        }
        return;
    }

    // ---- pair part ----
    const int tp = bx;  // 0..527, (ti<=tj) of 32x32 tiles
    int ti = (int)((65.0f - sqrtf(4225.0f - 8.0f * (float)tp)) * 0.5f);
    while ((ti + 1) * (65 - (ti + 1)) / 2 <= tp) ++ti;
    while (ti * (65 - ti) / 2 > tp) --ti;
    const int tj = ti + (tp - ti * (65 - ti) / 2);
    const int i0 = ti * 8, j0 = tj * 8;

    const int l = lane & 15, q = lane >> 4;
    const int xorv = (l & 7) << 4;

    // hoisted (batch-invariant) weights
    const __hip_bfloat16* wb0 = w2t + ((wave * 2 + 0) * 16 + l) * 256 + q * 8;
    const __hip_bfloat16* wb1 = wb0 + 16 * 256;
    const float b2v0 = cd_b2[(wave * 2 + 0) * 16 + l];
    const float b2v1 = cd_b2[(wave * 2 + 1) * 16 + l];
    const float w3v0 = cd_w3[(wave * 2 + 0) * 16 + l];
    const float w3v1 = cd_w3[(wave * 2 + 1) * 16 + l];
    const float b3 = cd_b3[0];

    f32x4 acc[4][2];
    float4 ru0[4], ru1[4], rv0[4], rv1[4];  // in-flight stage regs (T14)

    auto ISSUE = [&](int u, int h) {
        const float* Ub = Ug + ((u << 8) + i0) * 256 + (h << 7);
        const float* Vb = Vg + ((u << 8) + j0) * 256 + (h << 7);
        #pragma unroll
        for (int w = 0; w < 4; ++w) {
            int idx = (w << 8) + t;          // [64 pairs][16 chunks of 8]
            int p = idx >> 4, c = idx & 15;
            const float* up = Ub + (p >> 3) * 256 + c * 8;
            const float* vp = Vb + (p & 7) * 256 + c * 8;
            ru0[w] = *(const float4*)up;  ru1[w] = *(const float4*)(up + 4);
            rv0[w] = *(const float4*)vp;  rv1[w] = *(const float4*)(vp + 4);
        }
    };
    auto WRITE = [&](int buf) {
        char* dst = (char*)hsH[buf];
        #pragma unroll
        for (int w = 0; w < 4; ++w) {
            int idx = (w << 8) + t;
            int p = idx >> 4, c = idx & 15;
            bf16x8 o;
            o[0] = f2bf(fmaxf(ru0[w].x + rv0[w].x, 0.f));
            o[1] = f2bf(fmaxf(ru0[w].y + rv0[w].y, 0.f));
            o[2] = f2bf(fmaxf(ru0[w].z + rv0[w].z, 0.f));
            o[3] = f2bf(fmaxf(ru0[w].w + rv0[w].w, 0.f));
            o[4] = f2bf(fmaxf(ru1[w].x + rv1[w].x, 0.f));
            o[5] = f2bf(fmaxf(ru1[w].y + rv1[w].y, 0.f));
            o[6] = f2bf(fmaxf(ru1[w].z + rv1[w].z, 0.f));
            o[7] = f2bf(fmaxf(ru1[w].w + rv1[w].w, 0.f));
            int byte = (p << 8) + (((c << 4)) ^ ((p & 7) << 4));
            *(bf16x8*)(dst + byte) = o;
        }
    };
    auto MFMAH = [&](int h, int buf) {
        const char* src = (const char*)hsH[buf];
        #pragma unroll
        for (int ks = 0; ks < 4; ++ks) {
            bf16x8 bfr0 = *(const bf16x8*)(wb0 + (h * 4 + ks) * 32);
            bf16x8 bfr1 = *(const bf16x8*)(wb1 + (h * 4 + ks) * 32);
            #pragma unroll
            for (int mt = 0; mt < 4; ++mt) {
                int byte = (mt << 12) + (l << 8) + (((ks << 6) + (q << 4)) ^ xorv);
                bf16x8 afr = *(const bf16x8*)(src + byte);
                acc[mt][0] = __builtin_amdgcn_mfma_f32_16x16x32_bf16(afr, bfr0, acc[mt][0], 0, 0, 0);
                acc[mt][1] = __builtin_amdgcn_mfma_f32_16x16x32_bf16(afr, bfr1, acc[mt][1], 0, 0, 0);
            }
        }
    };
    auto EPI = [&](int u) {
        #pragma unroll
        for (int mt = 0; mt < 4; ++mt) {
            #pragma unroll
            for (int r = 0; r < 4; ++r) {
                float g0 = fmaxf(acc[mt][0][r] + b2v0, 0.f);
                float g1 = fmaxf(acc[mt][1][r] + b2v1, 0.f);
                float s = g0 * w3v0 + g1 * w3v1;
                s += __shfl_xor(s, 1);
                s += __shfl_xor(s, 2);
                s += __shfl_xor(s, 4);
                s += __shfl_xor(s, 8);
                if (l == 0) ps[u & 1][mt * 16 + q * 4 + r][wave] = s;
            }
        }
    };
    auto FIN = [&](int u) {
        if (t < 64) {
            int p = t;
            float v = ps[u & 1][p][0] + ps[u & 1][p][1] + ps[u & 1][p][2]
                    + ps[u & 1][p][3] + b3;
            float prob = 1.0f / (1.0f + __expf(-v));
            int i = i0 + (p >> 3), j = j0 + (p & 7);
            float* base = cm + u * 65536;
            if (i < j) {
                base[i * 256 + j] = prob;
                base[j * 256 + i] = prob;
            } else if (i == j) {
                base[i * 256 + i] = 0.0f;
            }
        }
    };

    // prologue: stage unit0/half0 into buf0
    ISSUE(0, 0);
    WRITE(0);
    __syncthreads();

    #pragma unroll
    for (int s = 1; s <= 8; ++s) {
        if (s < 8) ISSUE(s >> 1, s & 1);        // loads in flight during MFMA
        const int sp = s - 1, u = sp >> 1, h = sp & 1;
        if (h == 0) {
            #pragma unroll
            for (int mt = 0; mt < 4; ++mt) {
                acc[mt][0] = (f32x4){0.f, 0.f, 0.f, 0.f};
                acc[mt][1] = (f32x4){0.f, 0.f, 0.f, 0.f};
            }
        }
        MFMAH(h, h);                            // consume buf h (= sp&1)
        if (h == 1) EPI(u);                     // unit complete -> ps[u&1]
        if ((s & 1) && s >= 3) FIN((s - 3) >> 1);  // cm write, 1 unit behind
        if (s < 8) WRITE(s & 1);                // convert + ds_write late
        __syncthreads();
    }
    FIN(3);
}

// ---------------------------------------------------------------------------
extern "C" void kernel_launch(void* const* d_in, const int* in_sizes, int n_in,
                              void* d_out, int out_size, void* d_ws, size_t ws_size,
                              hipStream_t stream) {
    const float* x     = (const float*)d_in[0];
    const float* pp_w1 = (const float*)d_in[1];
    const float* pp_b1 = (const float*)d_in[2];
    const float* pp_w2 = (const float*)d_in[3];
    const float* pp_b2 = (const float*)d_in[4];
    const float* cd_w1 = (const float*)d_in[5];
    const float* cd_b1 = (const float*)d_in[6];
    const float* cd_w2 = (const float*)d_in[7];
    const float* cd_b2 = (const float*)d_in[8];
    const float* cd_w3 = (const float*)d_in[9];
    const float* cd_b3 = (const float*)d_in[10];
    const float* vel_w = (const float*)d_in[11];
    const float* vel_b = (const float*)d_in[12];
    const float* frc_w = (const float*)d_in[13];
    const float* frc_b = (const float*)d_in[14];

    float* out = (float*)d_out;
    // ws: Ug 1MB | Vg 1MB | xb 1MB | Wt 1MB | hidg 1MB | w2t 64KB | hw 20KB
    float* Ug = (float*)d_ws;
    float* Vg = Ug + 262144;
    __hip_bfloat16* xb   = (__hip_bfloat16*)(Vg + 262144);
    __hip_bfloat16* Wt   = xb + 524288;
    __hip_bfloat16* hidg = Wt + 524288;
    __hip_bfloat16* w2t  = hidg + 524288;
    float* hw = (float*)(w2t + 32768);

    convert_kernel<<<dim3(393), dim3(256), 0, stream>>>(
        x, pp_w1, cd_w1, cd_w2, pp_w2, vel_w, frc_w, xb, Wt, w2t, hw);
    gemm_kernel<<<dim3(8, 32), dim3(256), 0, stream>>>(
        xb, Wt, pp_b1, cd_b1, hidg, Ug, Vg);
    pair_kernel<<<dim3(656), dim3(256), 0, stream>>>(
        Ug, Vg, w2t, cd_b2, cd_w3, cd_b3, out + 10240,
        x, hidg, hw, pp_b2, vel_b, frc_b, out);
}